// Round 1
// baseline (68.046 us; speedup 1.0000x reference)
//
#include <hip/hip_runtime.h>

typedef float f4 __attribute__((ext_vector_type(4)));

#define TT 4096
#define CC 128
#define BB 32
#define NG 32          // t-groups for partial moments
#define C4 (CC / 4)    // 32 float4 per row
#define ROWS_G (TT / NG)  // 128 rows per moment block

// ---------------------------------------------------------------------------
// Kernel 1: partial moments m0 = sum x, m1 = sum u*x, m2 = sum u^2*x
// over a 128-row t-slab, per (b, c). 256 threads = 8 row-groups x 32 c-quads.
// ---------------------------------------------------------------------------
__global__ __launch_bounds__(256) void k_moments(const f4* __restrict__ x4,
                                                 f4* __restrict__ partial,
                                                 float scale) {
    const int blk = blockIdx.x;
    const int b = blk >> 5;    // / NG
    const int g = blk & 31;    // % NG
    const int tid = threadIdx.x;
    const int r = tid >> 5;    // 0..7  row sub-group
    const int q = tid & 31;    // 0..31 c-quad
    const f4* xb = x4 + (size_t)b * TT * C4;
    const int t0 = g * ROWS_G;

    f4 m0 = (f4)0.0f, m1 = (f4)0.0f, m2 = (f4)0.0f;
#pragma unroll
    for (int k = 0; k < ROWS_G / 8; ++k) {   // 16 iterations
        const int t = t0 + r + (k << 3);
        const float u = fmaf((float)t, scale, -0.5f);
        const f4 v = xb[(size_t)t * C4 + q];
        m0 += v;
        m1 += u * v;
        m2 += (u * u) * v;
    }

    __shared__ f4 red[3][8][32];
    red[0][r][q] = m0;
    red[1][r][q] = m1;
    red[2][r][q] = m2;
    __syncthreads();

    if (tid < 32) {
#pragma unroll
        for (int j = 0; j < 3; ++j) {
            f4 s = red[j][0][tid];
#pragma unroll
            for (int rr = 1; rr < 8; ++rr) s += red[j][rr][tid];
            partial[(size_t)blk * (3 * C4) + j * C4 + tid] = s;
        }
    }
}

// ---------------------------------------------------------------------------
// Kernel 1b: reduce NG partials and normalize with the orthogonal-basis
// scalars. coef layout: [B][3][C4] float4.
// ---------------------------------------------------------------------------
__global__ __launch_bounds__(64) void k_coef(const f4* __restrict__ partial,
                                             f4* __restrict__ coef,
                                             float invS0, float invS2,
                                             float invD, float c20) {
    const int b = blockIdx.x;
    const int q = threadIdx.x;
    if (q >= C4) return;
    f4 s0 = (f4)0.0f, s1 = (f4)0.0f, s2 = (f4)0.0f;
    const f4* p = partial + (size_t)b * NG * (3 * C4);
    for (int g = 0; g < NG; ++g) {
        s0 += p[g * (3 * C4) + 0 * C4 + q];
        s1 += p[g * (3 * C4) + 1 * C4 + q];
        s2 += p[g * (3 * C4) + 2 * C4 + q];
    }
    const f4 a0 = s0 * invS0;
    const f4 a1 = s1 * invS2;
    const f4 a2 = (s2 - c20 * s0) * invD;
    coef[(size_t)b * (3 * C4) + 0 * C4 + q] = a0;
    coef[(size_t)b * (3 * C4) + 1 * C4 + q] = a1;
    coef[(size_t)b * (3 * C4) + 2 * C4 + q] = a2;
}

// ---------------------------------------------------------------------------
// Kernel 2: low = a0 + u*a1 + (u^2 - c20)*a2 ; res = x - low.
// 64-row tiles; nontemporal streaming stores (never re-read; keep x in L3).
// ---------------------------------------------------------------------------
__global__ __launch_bounds__(256) void k_emit(const f4* __restrict__ x4,
                                              const f4* __restrict__ coef,
                                              f4* __restrict__ out_low,
                                              f4* __restrict__ out_res,
                                              float scale, float c20) {
    const int blk = blockIdx.x;
    const int b = blk >> 6;    // 64 tiles per batch
    const int tile = blk & 63;
    const int tid = threadIdx.x;
    const int r = tid >> 5;
    const int q = tid & 31;

    __shared__ f4 ca[3 * C4];
    if (tid < 3 * C4) ca[tid] = coef[(size_t)b * (3 * C4) + tid];
    __syncthreads();

    const f4 a0 = ca[0 * C4 + q];
    const f4 a1 = ca[1 * C4 + q];
    const f4 a2 = ca[2 * C4 + q];

    const size_t base = (size_t)b * TT * C4;
    const int t0 = tile * 64;
#pragma unroll
    for (int k = 0; k < 8; ++k) {
        const int t = t0 + r + (k << 3);
        const float u = fmaf((float)t, scale, -0.5f);
        const float w = fmaf(u, u, -c20);
        const size_t idx = base + (size_t)t * C4 + q;
        const f4 xv = x4[idx];
        const f4 lo = a0 + u * a1 + w * a2;
        const f4 re = xv - lo;
        __builtin_nontemporal_store(lo, &out_low[idx]);
        __builtin_nontemporal_store(re, &out_res[idx]);
    }
}

// ---------------------------------------------------------------------------
extern "C" void kernel_launch(void* const* d_in, const int* in_sizes, int n_in,
                              void* d_out, int out_size, void* d_ws, size_t ws_size,
                              hipStream_t stream) {
    const float* x = (const float*)d_in[0];
    float* out = (float*)d_out;
    const size_t N = (size_t)BB * TT * CC;   // 16,777,216

    float* out_low = out;            // output 0
    float* out_res = out + N;        // output 1 (highs[0])
    // Use the zero-output regions as scratch; they are memset to 0 LAST,
    // after all kernels that read them have run (stream-ordered).
    float* partial = out + 2 * N;    // 1.5 MB of partial moments
    float* coef    = out + 3 * N;    // 48 KB of coefficients

    // Exact basis scalars in double on host (t symmetric => S1 = S3 = 0).
    double S0 = (double)TT, S2 = 0.0, S4 = 0.0;
    for (int i = 0; i < TT; ++i) {
        double u = (double)i / (double)(TT - 1) - 0.5;
        double u2 = u * u;
        S2 += u2;
        S4 += u2 * u2;
    }
    const double c20d = S2 / S0;               // mean of u^2
    const double Dd = S4 - S2 * S2 / S0;       // ||u^2 - c20||^2
    const float scale = (float)(1.0 / (double)(TT - 1));

    k_moments<<<BB * NG, 256, 0, stream>>>((const f4*)x, (f4*)partial, scale);
    k_coef<<<BB, 64, 0, stream>>>((const f4*)partial, (f4*)coef,
                                  (float)(1.0 / S0), (float)(1.0 / S2),
                                  (float)(1.0 / Dd), (float)c20d);
    k_emit<<<BB * 64, 256, 0, stream>>>((const f4*)x, (const f4*)coef,
                                        (f4*)out_low, (f4*)out_res, scale,
                                        (float)c20d);
    // Zero the two "high" outputs (also wipes the scratch living there).
    hipMemsetAsync(out + 2 * N, 0, 2 * N * sizeof(float), stream);
}